// Round 1
// baseline (65.218 us; speedup 1.0000x reference)
//
#include <hip/hip_runtime.h>

// CausalityMapBlock, B=2 C=128 H=W=7 F=49, p=1.
// Closed form: with p=1 the pairwise Lehmer numerator over the F*F outer
// product collapses to rank-1 expressions in per-channel sums S1, S2:
//   num[m,n] = S2m*S2n + 2*EPS*S1m*S1n + F^2*EPS^2 + EPS
//   den[m,n] = S1m*S1n + F^2*EPS + EPS
//   ld[c]    = (S2 + 2*EPS*S1 + F*EPS^2 + EPS) / (S1 + F*EPS + EPS) + EPS
//   out[b,m,n] = (num/den + EPS) / ld[b,n]
// All nan_to_num are no-ops (x uniform [0,1), batch max > 0).

constexpr float EPS = 1e-8f;
constexpr int B = 2, C = 128, F = 49;
constexpr int NIN  = B * C * F;   // 12544
constexpr int HALF = NIN / 2;     // 6272 (per-batch element count)
constexpr int NOUT = B * C * C;   // 32768
constexpr int BLK  = 1024;

__global__ __launch_bounds__(BLK)
void causality_kernel(const float* __restrict__ x, float* __restrict__ out) {
    __shared__ float sx[NIN];                 // 50176 B staged input
    __shared__ float s1[B * C];
    __shared__ float s2[B * C];
    __shared__ float ld[B * C];               // per-channel lehmer denominator
    __shared__ float rmax0[BLK / 64], rmax1[BLK / 64];
    __shared__ float bmax[B];

    const int tid  = threadIdx.x;
    const int lane = tid & 63;
    const int wid  = tid >> 6;

    // ---- stage input to LDS, fold per-batch max on the fly ----
    float m0 = 0.f, m1 = 0.f;
    for (int i = tid; i < NIN; i += BLK) {
        float v = x[i];
        sx[i] = v;
        if (i < HALF) m0 = fmaxf(m0, v);
        else          m1 = fmaxf(m1, v);
    }
#pragma unroll
    for (int off = 32; off > 0; off >>= 1) {
        m0 = fmaxf(m0, __shfl_down(m0, off));
        m1 = fmaxf(m1, __shfl_down(m1, off));
    }
    if (lane == 0) { rmax0[wid] = m0; rmax1[wid] = m1; }
    __syncthreads();
    if (tid == 0) {
        float a = rmax0[0], b = rmax1[0];
        for (int w = 1; w < BLK / 64; ++w) {
            a = fmaxf(a, rmax0[w]);
            b = fmaxf(b, rmax1[w]);
        }
        bmax[0] = a; bmax[1] = b;
    }
    __syncthreads();

    // ---- per-channel S1/S2: 4 threads per channel (4*256 == 1024) ----
    {
        const int bc  = tid >> 2;   // 0..255
        const int sub = tid & 3;
        float a1 = 0.f, a2 = 0.f;
        const float* p = sx + bc * F;
        for (int k = sub; k < F; k += 4) {
            float v = p[k];
            a1 += v;
            a2 += v * v;
        }
        // groups of 4 never straddle a wave boundary
        a1 += __shfl_down(a1, 2); a2 += __shfl_down(a2, 2);
        a1 += __shfl_down(a1, 1); a2 += __shfl_down(a2, 1);
        if (sub == 0) {
            const float inv = 1.f / (bmax[bc >> 7] + EPS);
            const float S1 = a1 * inv;
            const float S2 = a2 * inv * inv;
            s1[bc] = S1;
            s2[bc] = S2;
            const float nd = S2 + 2.f * EPS * S1 + (float)F * EPS * EPS + EPS;
            const float dd = S1 + (float)F * EPS + EPS;
            ld[bc] = nd / dd + EPS;
        }
    }
    __syncthreads();

    // ---- 32768 outputs, 32 per thread, coalesced stores ----
    constexpr float F2 = (float)(F * F);  // 2401
    for (int idx = tid; idx < NOUT; idx += BLK) {
        const int b  = idx >> 14;
        const int m  = (idx >> 7) & (C - 1);
        const int n  = idx & (C - 1);
        const int bm = (b << 7) | m;
        const int bn = (b << 7) | n;
        const float num = s2[bm] * s2[bn] + 2.f * EPS * (s1[bm] * s1[bn])
                          + F2 * EPS * EPS + EPS;
        const float den = s1[bm] * s1[bn] + F2 * EPS + EPS;
        const float ln  = num / den + EPS;
        out[idx] = ln / ld[bn];
    }
}

extern "C" void kernel_launch(void* const* d_in, const int* in_sizes, int n_in,
                              void* d_out, int out_size, void* d_ws, size_t ws_size,
                              hipStream_t stream) {
    const float* x = (const float*)d_in[0];
    float* out = (float*)d_out;
    causality_kernel<<<1, BLK, 0, stream>>>(x, out);
}

// Round 2
// 53.167 us; speedup vs baseline: 1.2267x; 1.2267x over previous
//
#include <hip/hip_runtime.h>

// CausalityMapBlock, B=2 C=128 H=W=7 F=49, p=1.
// Closed form (p=1): the B*C*C*F*F einsum collapses to rank-1 expressions in
// per-channel sums of the max-normalized input, S1[c] = sum_i x[c,i],
// S2[c] = sum_i x[c,i]^2:
//   num[m,n] = S2m*S2n + 2*EPS*S1m*S1n + F^2*EPS^2 + EPS
//   den[m,n] = S1m*S1n + F^2*EPS + EPS
//   ld[c]    = (S2 + 2*EPS*S1 + F*EPS^2 + EPS) / (S1 + F*EPS + EPS) + EPS
//   out[b,m,n] = (num/den + EPS) / ld[b,n]
// All nan_to_num are no-ops (x uniform [0,1), batch max > 0).
// Normalization deferred: S1 = S1raw/(M+EPS), S2 = S2raw/(M+EPS)^2.
//
// Structure: 64 blocks x 256 threads. Stats are redundantly computed per block
// (50 KB input, L2-resident after first touch) so there is no inter-block
// dependency; each block writes 512 of the 32768 outputs, coalesced.
// Divides use v_rcp_f32 (rel err ~1e-6, threshold 1.5e-2).

constexpr float EPS = 1e-8f;
constexpr int B = 2, C = 128, F = 49;
constexpr int NIN  = B * C * F;    // 12544
constexpr int N4   = NIN / 4;      // 3136 float4s
constexpr int BC   = B * C;        // 256
constexpr int NOUT = B * C * C;    // 32768
constexpr int BLK  = 256;
constexpr int GRID = 64;           // 512 outputs per block, 2 per thread

__global__ __launch_bounds__(BLK)
void causality_kernel(const float* __restrict__ x, float* __restrict__ out) {
    __shared__ __align__(16) float sx[NIN];   // 50176 B
    __shared__ float s1[BC], s2[BC], rld[BC];
    __shared__ float wmax[BLK / 64];

    const int tid  = threadIdx.x;
    const int lane = tid & 63;
    const int wid  = tid >> 6;

    // ---- coalesced float4 stage to LDS ----
    const float4* __restrict__ x4 = (const float4*)x;
    float4* sx4 = (float4*)sx;
#pragma unroll
    for (int i = 0; i < 12; ++i) sx4[tid + i * BLK] = x4[tid + i * BLK];
    if (tid < N4 - 12 * BLK) sx4[tid + 12 * BLK] = x4[tid + 12 * BLK];
    __syncthreads();

    // ---- thread tid == channel (b,c); raw sums + channel max in one pass ----
    float a1 = 0.f, a2 = 0.f, mx = 0.f;
    const float* p = sx + tid * F;   // bank stride 49*4B: 2-way alias, free
#pragma unroll
    for (int k = 0; k < F; ++k) {
        float v = p[k];
        a1 += v;
        a2 += v * v;
        mx = fmaxf(mx, v);
    }

    // ---- batch max: waves 0,1 -> batch 0; waves 2,3 -> batch 1 ----
    float m = mx;
#pragma unroll
    for (int off = 32; off > 0; off >>= 1) m = fmaxf(m, __shfl_down(m, off));
    if (lane == 0) wmax[wid] = m;
    __syncthreads();
    const int wb = (tid >> 7) << 1;                       // 0 or 2
    const float bmax = fmaxf(wmax[wb], wmax[wb + 1]);

    // ---- per-channel stats ----
    const float inv = __builtin_amdgcn_rcpf(bmax + EPS);
    const float S1 = a1 * inv;
    const float S2 = a2 * inv * inv;
    s1[tid] = S1;
    s2[tid] = S2;
    const float nd  = S2 + 2.f * EPS * S1 + (float)F * EPS * EPS + EPS;
    const float dd  = S1 + (float)F * EPS + EPS;
    const float ldv = nd * __builtin_amdgcn_rcpf(dd) + EPS;
    rld[tid] = __builtin_amdgcn_rcpf(ldv);
    __syncthreads();

    // ---- 512 outputs per block, coalesced ----
    constexpr float F2 = (float)(F * F);   // 2401
    const int base = blockIdx.x * (NOUT / GRID);
#pragma unroll
    for (int j = 0; j < NOUT / GRID / BLK; ++j) {
        const int idx = base + tid + j * BLK;
        const int bb  = (idx >> 14) << 7;
        const int bm  = bb | ((idx >> 7) & (C - 1));
        const int bn  = bb | (idx & (C - 1));
        const float P   = s1[bm] * s1[bn];
        const float num = s2[bm] * s2[bn] + 2.f * EPS * P + F2 * EPS * EPS + EPS;
        const float den = P + F2 * EPS + EPS;
        const float ln  = num * __builtin_amdgcn_rcpf(den) + EPS;
        out[idx] = ln * rld[bn];
    }
}

extern "C" void kernel_launch(void* const* d_in, const int* in_sizes, int n_in,
                              void* d_out, int out_size, void* d_ws, size_t ws_size,
                              hipStream_t stream) {
    const float* x = (const float*)d_in[0];
    float* out = (float*)d_out;
    causality_kernel<<<GRID, BLK, 0, stream>>>(x, out);
}